// Round 7
// baseline (288.744 us; speedup 1.0000x reference)
//
#include <hip/hip_runtime.h>
#include <cstdint>

#define NBATCH 4
#define NPATCH 4096
#define MAXC   5
#define NCHUNK 6                            /* col chunks (j) */
#define RBLOCKS 32                          /* 128-row blocks per batch */
#define GRID_MAIN (NBATCH * RBLOCKS * NCHUNK)   /* 768 4-wave blocks = 3/CU */
#define SCALE  14.285714285714286f          /* 1/T, T=0.07 */
#define SCALE2 20.609929006188747f          /* (1/T) * log2(e) */
#define LN2F   0.6931471805599453f
#define NEGH  -1.0e38f
#define NEGFILL_T -142.85714285714286f      /* NEG_FILL / T */
#define NROWS (NBATCH * NPATCH)

typedef __attribute__((ext_vector_type(8))) short short8;   // 8 bf16 (4 VGPRs)
typedef __attribute__((ext_vector_type(4))) float f32x4;
typedef __attribute__((ext_vector_type(4))) unsigned int u32x4;

__device__ __forceinline__ float fexp2(float x) { return __builtin_amdgcn_exp2f(x); }
__device__ __forceinline__ float flog2(float x) { return __builtin_amdgcn_logf(x); }  // v_log_f32 = log2

__device__ __forceinline__ unsigned short f2bf(float f) {
  uint32_t u = __builtin_bit_cast(uint32_t, f);
  u = (u + 0x7FFFu + ((u >> 16) & 1u)) >> 16;   // RNE
  return (unsigned short)u;
}

// async global->LDS, 16B per lane; LDS dest is wave-uniform base + lane*16
__device__ __forceinline__ void glds16(const void* g, void* l) {
  __builtin_amdgcn_global_load_lds(
      (const __attribute__((address_space(1))) uint32_t*)g,
      (__attribute__((address_space(3))) uint32_t*)l, 16, 0, 0);
}

// Fragment layout (srcb and tgtb): tile = 16 rows x 256 k (8 KB).
// 16B chunk (8 bf16, one row's k-octet) at uint4 index  tile*512 + kc*16 + row16.

// ---- k_aux copy body (shared by real kernel and x8 probe) ----
__device__ __forceinline__ void aux_copy_body(const float* __restrict__ src,
                                              const float* __restrict__ tgt,
                                              unsigned short* __restrict__ tgtb,
                                              unsigned short* __restrict__ srcb,
                                              float* __restrict__ pos,
                                              int blk, int t) {
  int tl = blk * 2 + (t >> 7);
  int tt = t & 127;
  int row16 = tt >> 3;
  int kg    = tt & 7;
  size_t rowbase = (size_t)(tl * 16 + row16) * 256 + kg * 32;
  const float4* rs = (const float4*)(src + rowbase);
  const float4* rt_ = (const float4*)(tgt + rowbase);
  uint4* wsrc = (uint4*)srcb + (size_t)tl * 512 + (size_t)(kg * 4) * 16 + row16;
  uint4* wtgt = (uint4*)tgtb + (size_t)tl * 512 + (size_t)(kg * 4) * 16 + row16;
  float d = 0.f;
#pragma unroll
  for (int j = 0; j < 4; ++j) {
    float4 sa = rs[j * 2], sb = rs[j * 2 + 1];
    float4 ta = rt_[j * 2], tb = rt_[j * 2 + 1];
    d += sa.x * ta.x + sa.y * ta.y + sa.z * ta.z + sa.w * ta.w
       + sb.x * tb.x + sb.y * tb.y + sb.z * tb.z + sb.w * tb.w;
    union { ushort4 h[2]; uint4 u; } pk;
    pk.h[0].x = f2bf(sa.x * SCALE2); pk.h[0].y = f2bf(sa.y * SCALE2);
    pk.h[0].z = f2bf(sa.z * SCALE2); pk.h[0].w = f2bf(sa.w * SCALE2);
    pk.h[1].x = f2bf(sb.x * SCALE2); pk.h[1].y = f2bf(sb.y * SCALE2);
    pk.h[1].z = f2bf(sb.z * SCALE2); pk.h[1].w = f2bf(sb.w * SCALE2);
    wsrc[j * 16] = pk.u;
    pk.h[0].x = f2bf(ta.x); pk.h[0].y = f2bf(ta.y);
    pk.h[0].z = f2bf(ta.z); pk.h[0].w = f2bf(ta.w);
    pk.h[1].x = f2bf(tb.x); pk.h[1].y = f2bf(tb.y);
    pk.h[1].z = f2bf(tb.z); pk.h[1].w = f2bf(tb.w);
    wtgt[j * 16] = pk.u;
  }
  d += __shfl_xor(d, 1, 64);
  d += __shfl_xor(d, 2, 64);
  d += __shfl_xor(d, 4, 64);
  if (kg == 0) pos[tl * 16 + row16] = d * SCALE;
}

// ---- k_aux: 2 roles ----  (identical behavior to R4/R5)
__global__ __launch_bounds__(256) void k_aux(const float* __restrict__ src,
                                             const float* __restrict__ tgt,
                                             const int* __restrict__ classes,
                                             unsigned short* __restrict__ tgtb,
                                             unsigned short* __restrict__ srcb,
                                             float* __restrict__ pos,
                                             int* __restrict__ outpos,
                                             int* __restrict__ counts) {
  int blk = blockIdx.x;
  if (blk < 512) {
    aux_copy_body(src, tgt, tgtb, srcb, pos, blk, threadIdx.x);
    return;
  }

  __shared__ int sa[MAXC * 256];
  __shared__ int sb2[MAXC * 256];
  int b = blk - 512, t = threadIdx.x;
  int base = b * NPATCH + t * 16;
  int cv[16];
#pragma unroll
  for (int e = 0; e < 16; ++e) cv[e] = classes[base + e];
  int cnt[MAXC];
#pragma unroll
  for (int c = 0; c < MAXC; ++c) {
    cnt[c] = 0;
#pragma unroll
    for (int e = 0; e < 16; ++e)
      if (cv[e] == c) cnt[c]++;
  }
#pragma unroll
  for (int c = 0; c < MAXC; ++c) sa[c * 256 + t] = cnt[c];
  __syncthreads();

  int* rp = sa; int* wp = sb2;
  for (int d = 1; d < 256; d <<= 1) {
#pragma unroll
    for (int c = 0; c < MAXC; ++c) {
      int v = rp[c * 256 + t];
      if (t >= d) v += rp[c * 256 + t - d];
      wp[c * 256 + t] = v;
    }
    __syncthreads();
    int* tmp = rp; rp = wp; wp = tmp;
  }

  int tot[MAXC], excl[MAXC], off[MAXC + 1];
  off[0] = 0;
#pragma unroll
  for (int c = 0; c < MAXC; ++c) {
    tot[c]  = rp[c * 256 + 255];
    excl[c] = rp[c * 256 + t] - cnt[c];
    off[c + 1] = off[c] + tot[c];
  }
#pragma unroll
  for (int c = 0; c < MAXC; ++c) {
    int r = off[c] + excl[c];
#pragma unroll
    for (int e = 0; e < 16; ++e)
      if (cv[e] == c) { outpos[base + e] = r; r++; }
  }
  if (t < MAXC) counts[b * MAXC + t] = tot[t];
}

// ---- PROBE: copy part x8 (idempotent; memory clobber defeats dedup).  dur/8 = k_aux
// copy cost.  Grid 512.
__global__ __launch_bounds__(256) void k_aux_probe(const float* __restrict__ src,
                                                   const float* __restrict__ tgt,
                                                   unsigned short* __restrict__ tgtb,
                                                   unsigned short* __restrict__ srcb,
                                                   float* __restrict__ pos) {
  for (int rep = 0; rep < 8; ++rep) {
    aux_copy_body(src, tgt, tgtb, srcb, pos, blockIdx.x, threadIdx.x);
    asm volatile("" ::: "memory");
  }
}

// ---------------- main fused GEMM + online lse stats -----------------------------------
// R6 measurement build.  Template: <NOSTATS, FULLRANGE>.
//  <0,0> = real kernel (identical to R5's measured binary, pins kept).
//  <1,1> = probe: STATS -> asm keepalive (no DCE of MFMAs, rule #17), nt = all 128
//          col-tiles (6x work -> tops the top-5 table).  GEMM-side cost/tile = dur/128.
template <int NOSTATS, int FULLRANGE>
__global__ __launch_bounds__(256, 3) void k_main_t(const unsigned short* __restrict__ srcb,
                                                   const unsigned short* __restrict__ tgtb,
                                                   const int* __restrict__ classes,
                                                   float* __restrict__ pm,
                                                   float* __restrict__ ps) {
  __shared__ u32x4 sB[2][1024];               // 2 x 16KB B-tile buffers

  const int p   = blockIdx.x;
  const int b   = p & 3;
  const int jl  = (p >> 2) & 1;
  const int rb  = (p >> 3) & 31;
  const int top = p >> 8;                     // 0..2
  const int j   = top * 2 + jl;               // 0..5
  const int t0  = FULLRANGE ? 0   : (j * 64) / 3;
  const int t1  = FULLRANGE ? 128 : ((j + 1) * 64) / 3;
  const int nt  = t1 - t0;

  const int tid  = threadIdx.x;
  const int w    = tid >> 6;                  // wave 0..3 -> rowgroup
  const int lane = tid & 63;
  const int q = lane >> 4, l4 = lane & 15;
  const int rowstart = b * NPATCH + rb * 128 + w * 32;

  // ---- A fragments: 32 rows resident per wave (16 coalesced uint4 loads), pinned
  const u32x4* ap = (const u32x4*)srcb + (size_t)(b * 256 + rb * 8 + w * 2) * 512 + lane;
  u32x4 afr[2][8];
#pragma unroll
  for (int rt = 0; rt < 2; ++rt)
#pragma unroll
    for (int ks = 0; ks < 8; ++ks)
      afr[rt][ks] = ap[rt * 512 + ks * 64];
#pragma unroll
  for (int rt = 0; rt < 2; ++rt)
#pragma unroll
    for (int ks = 0; ks < 8; ++ks)
      asm volatile("" : "+v"(afr[rt][ks]));

  int rcls[2][4];
#pragma unroll
  for (int rt = 0; rt < 2; ++rt)
#pragma unroll
    for (int r = 0; r < 4; ++r) {
      rcls[rt][r] = classes[rowstart + rt * 16 + q * 4 + r];
      asm volatile("" : "+v"(rcls[rt][r]));
    }

  float m_[2][4], s_[2][4];
#pragma unroll
  for (int rt = 0; rt < 2; ++rt)
#pragma unroll
    for (int r = 0; r < 4; ++r) { m_[rt][r] = -INFINITY; s_[rt][r] = 0.f; }

  const u32x4* bstage = (const u32x4*)tgtb + (size_t)(b * 256 + t0 * 2) * 512
                      + w * 64 + lane;
  const int* clp = classes + b * NPATCH + t0 * 32 + l4;

#define STAGE(NB, IT)                                                               \
  {                                                                                 \
    const u32x4* g = bstage + (size_t)(IT) * 1024;                                  \
    _Pragma("unroll")                                                               \
    for (int r = 0; r < 4; ++r)                                                     \
      glds16(g + r * 256, &sB[NB][(r * 4 + w) * 64]);                               \
  }

#define STATS(ac, cc0, cc1)                                                         \
  {                                                                                 \
    _Pragma("unroll")                                                               \
    for (int rt = 0; rt < 2; ++rt) {                                                \
      _Pragma("unroll")                                                             \
      for (int r = 0; r < 4; ++r) {                                                 \
        int rc = rcls[rt][r];                                                       \
        float y0 = ((cc0) == rc) ? NEGH : (ac)[rt][0][r];                           \
        float y1 = ((cc1) == rc) ? NEGH : (ac)[rt][1][r];                           \
        float nm = fmaxf(m_[rt][r], fmaxf(y0, y1));                                 \
        float e01 = fexp2(y0 - nm) + fexp2(y1 - nm);                                \
        s_[rt][r] = fmaf(s_[rt][r], fexp2(m_[rt][r] - nm), e01);                    \
        m_[rt][r] = nm;                                                             \
      }                                                                             \
    }                                                                               \
  }

  // keepalive: consumes acc + classes without computing stats (prevents MFMA DCE)
#define KEEP(ac, cc0, cc1)                                                          \
  {                                                                                 \
    asm volatile("" :: "v"((ac)[0][0]), "v"((ac)[0][1]),                            \
                       "v"((ac)[1][0]), "v"((ac)[1][1]), "v"(cc0), "v"(cc1));       \
  }

  const f32x4 zc = {0.f, 0.f, 0.f, 0.f};

  STAGE(0, 0);                                // prologue: tile 0 -> buf 0
  __syncthreads();                            // implicit vmcnt(0) drain

  int cb = 0;
  for (int it = 0; it < nt; ++it) {
    if (it + 1 < nt) STAGE(cb ^ 1, it + 1);   // prefetch next tile (drained at barrier)

    int c0 = clp[0];                          // this tile's column classes
    int c1 = clp[16];
    clp += 32;

    f32x4 acc[2][2];
    {                                         // kh = 0
      u32x4 e0[4], e1[4];
#pragma unroll
      for (int i = 0; i < 4; ++i) {
        e0[i] = sB[cb][i * 64 + lane];
        e1[i] = sB[cb][512 + i * 64 + lane];
      }
#pragma unroll
      for (int ksl = 0; ksl < 4; ++ksl) {
        short8 b0 = __builtin_bit_cast(short8, e0[ksl]);
        short8 b1 = __builtin_bit_cast(short8, e1[ksl]);
#pragma unroll
        for (int rt = 0; rt < 2; ++rt) {
          short8 a = __builtin_bit_cast(short8, afr[rt][ksl]);
          acc[rt][0] = __builtin_amdgcn_mfma_f32_16x16x32_bf16(
              a, b0, (ksl == 0) ? zc : acc[rt][0], 0, 0, 0);
          acc[rt][1] = __builtin_amdgcn_mfma_f32_16x16x32_bf16(
              a, b1, (ksl == 0) ? zc : acc[rt][1], 0, 0, 0);
        }
      }
    }
    {                                         // kh = 1
      u32x4 e0[4], e1[4];
#pragma unroll
      for (int i = 0; i < 4; ++i) {
        e0[i] = sB[cb][256 + i * 64 + lane];
        e1[i] = sB[cb][768 + i * 64 + lane];
      }
#pragma unroll
      for (int ksl = 0; ksl < 4; ++ksl) {
        short8 b0 = __builtin_bit_cast(short8, e0[ksl]);
        short8 b1 = __builtin_bit_cast(short8, e1[ksl]);
#pragma unroll
        for (int rt = 0; rt < 2; ++rt) {
          short8 a = __builtin_bit_cast(short8, afr[rt][4 + ksl]);
          acc[rt][0] = __builtin_amdgcn_mfma_f32_16x16x32_bf16(a, b0, acc[rt][0], 0, 0, 0);
          acc[rt][1] = __builtin_amdgcn_mfma_f32_16x16x32_bf16(a, b1, acc[rt][1], 0, 0, 0);
        }
      }
    }

    if (NOSTATS) { KEEP(acc, c0, c1); } else { STATS(acc, c0, c1); }

    if (it + 1 < nt) { __syncthreads(); cb ^= 1; }
  }
#undef STAGE
#undef STATS
#undef KEEP

  // butterfly merge across the 16 col-lanes of each quad
#pragma unroll
  for (int off = 1; off < 16; off <<= 1) {
#pragma unroll
    for (int rt = 0; rt < 2; ++rt)
#pragma unroll
      for (int r = 0; r < 4; ++r) {
        float om = __shfl_xor(m_[rt][r], off, 64);
        float os = __shfl_xor(s_[rt][r], off, 64);
        float nm = fmaxf(m_[rt][r], om);
        s_[rt][r] = s_[rt][r] * fexp2(m_[rt][r] - nm) + os * fexp2(om - nm);
        m_[rt][r] = nm;
      }
  }

  if (l4 == 0) {
#pragma unroll
    for (int rt = 0; rt < 2; ++rt)
#pragma unroll
      for (int r = 0; r < 4; ++r) {
        size_t o = (size_t)j * NROWS + rowstart + rt * 16 + q * 4 + r;
        pm[o] = m_[rt][r];                     // log2 domain
        ps[o] = s_[rt][r];
      }
  }
}

// ---------------- final: merge chunk partials + pad term + scatter (grid 64) ----------
__global__ __launch_bounds__(256) void k_fin(const int* __restrict__ classes,
                                             const float* __restrict__ pos,
                                             const float* __restrict__ pm,
                                             const float* __restrict__ ps,
                                             const int* __restrict__ outpos,
                                             const int* __restrict__ counts,
                                             float* __restrict__ out) {
  int n = blockIdx.x * 256 + threadIdx.x;
  int b = n >> 12;
  int c = classes[n];
  float ps_ = pos[n];

  float M2 = -INFINITY;
  float mm[NCHUNK], ss[NCHUNK];
#pragma unroll
  for (int s = 0; s < NCHUNK; ++s) {
    mm[s] = pm[(size_t)s * NROWS + n];
    ss[s] = ps[(size_t)s * NROWS + n];
    M2 = fmaxf(M2, mm[s]);
  }
  float S2 = 0.f;
#pragma unroll
  for (int s = 0; s < NCHUNK; ++s) S2 = fmaf(ss[s], fexp2(mm[s] - M2), S2);
  float ln = (S2 > 0.f) ? (M2 + flog2(S2)) * LN2F : -INFINITY;

  int npad = counts[b * MAXC + c] - 1;
  float pt = (npad > 0) ? (logf((float)npad) + NEGFILL_T) : -INFINITY;
  float M = fmaxf(ps_, fmaxf(ln, pt));
  float lse = M + logf(expf(ps_ - M) + expf(ln - M) + expf(pt - M));
  out[b * NPATCH + outpos[n]] = lse - ps_;
}

extern "C" void kernel_launch(void* const* d_in, const int* in_sizes, int n_in,
                              void* d_out, int out_size, void* d_ws, size_t ws_size,
                              hipStream_t stream) {
  const float* src = (const float*)d_in[0];
  const float* tgt = (const float*)d_in[1];
  const int* cls   = (const int*)d_in[2];
  float* out = (float*)d_out;

  char* ws = (char*)d_ws;
  unsigned short* tgtb = (unsigned short*)(ws);            //  8,388,608 B (fragment layout)
  unsigned short* srcb = (unsigned short*)(ws + 8388608);  //  8,388,608 B (frag, pre-scaled)
  float* pos    = (float*)(ws + 16777216);                 //     65,536 B
  float* pm     = (float*)(ws + 16842752);                 //    393,216 B (6 chunk planes)
  float* ps     = (float*)(ws + 17235968);                 //    393,216 B
  int*   outpos = (int*)  (ws + 17629184);                 //     65,536 B
  int*   counts = (int*)  (ws + 17694720);                 //         80 B

  // real chain + probes (probes only touch ws regions rewritten before consumption)
  k_aux<<<512 + NBATCH, 256, 0, stream>>>(src, tgt, cls, tgtb, srcb, pos, outpos, counts);
  k_aux_probe<<<512, 256, 0, stream>>>(src, tgt, tgtb, srcb, pos);      // dur/8 = aux copy
  k_main_t<1, 1><<<GRID_MAIN, 256, 0, stream>>>(srcb, tgtb, cls, pm, ps); // dur/128 = GEMM/tile
  k_main_t<0, 0><<<GRID_MAIN, 256, 0, stream>>>(srcb, tgtb, cls, pm, ps); // real
  k_fin<<<NROWS / 256, 256, 0, stream>>>(cls, pos, pm, ps, outpos, counts, out);
}

// Round 8
// 128.144 us; speedup vs baseline: 2.2533x; 2.2533x over previous
//
#include <hip/hip_runtime.h>
#include <cstdint>

#define NBATCH 4
#define NPATCH 4096
#define MAXC   5
#define NCHUNK 6                            /* col chunks (j) */
#define RBLOCKS 32                          /* 128-row blocks per batch */
#define GRID_MAIN (NBATCH * RBLOCKS * NCHUNK)   /* 768 4-wave blocks = 3/CU */
#define SCALE  14.285714285714286f          /* 1/T, T=0.07 */
#define SCALE2 20.609929006188747f          /* (1/T) * log2(e) */
#define LN2F   0.6931471805599453f
#define NEGH  -1.0e38f
#define NEGFILL_T -142.85714285714286f      /* NEG_FILL / T */
#define NROWS (NBATCH * NPATCH)

typedef __attribute__((ext_vector_type(8))) short short8;   // 8 bf16 (4 VGPRs)
typedef __attribute__((ext_vector_type(4))) float f32x4;
typedef __attribute__((ext_vector_type(4))) unsigned int u32x4;

__device__ __forceinline__ float fexp2(float x) { return __builtin_amdgcn_exp2f(x); }
__device__ __forceinline__ float flog2(float x) { return __builtin_amdgcn_logf(x); }  // v_log_f32 = log2

__device__ __forceinline__ unsigned short f2bf(float f) {
  uint32_t u = __builtin_bit_cast(uint32_t, f);
  u = (u + 0x7FFFu + ((u >> 16) & 1u)) >> 16;   // RNE
  return (unsigned short)u;
}

// async global->LDS, 16B per lane; LDS dest is wave-uniform base + lane*16
__device__ __forceinline__ void glds16(const void* g, void* l) {
  __builtin_amdgcn_global_load_lds(
      (const __attribute__((address_space(1))) uint32_t*)g,
      (__attribute__((address_space(3))) uint32_t*)l, 16, 0, 0);
}

// Fragment layout (srcb and tgtb): tile = 16 rows x 256 k (8 KB).
// 16B chunk (8 bf16, one row's k-octet) at uint4 index  tile*512 + kc*16 + row16.

// ---- k_aux copy body ----
__device__ __forceinline__ void aux_copy_body(const float* __restrict__ src,
                                              const float* __restrict__ tgt,
                                              unsigned short* __restrict__ tgtb,
                                              unsigned short* __restrict__ srcb,
                                              float* __restrict__ pos,
                                              int blk, int t) {
  int tl = blk * 2 + (t >> 7);
  int tt = t & 127;
  int row16 = tt >> 3;
  int kg    = tt & 7;
  size_t rowbase = (size_t)(tl * 16 + row16) * 256 + kg * 32;
  const float4* rs = (const float4*)(src + rowbase);
  const float4* rt_ = (const float4*)(tgt + rowbase);
  uint4* wsrc = (uint4*)srcb + (size_t)tl * 512 + (size_t)(kg * 4) * 16 + row16;
  uint4* wtgt = (uint4*)tgtb + (size_t)tl * 512 + (size_t)(kg * 4) * 16 + row16;
  float d = 0.f;
#pragma unroll
  for (int j = 0; j < 4; ++j) {
    float4 sa = rs[j * 2], sb = rs[j * 2 + 1];
    float4 ta = rt_[j * 2], tb = rt_[j * 2 + 1];
    d += sa.x * ta.x + sa.y * ta.y + sa.z * ta.z + sa.w * ta.w
       + sb.x * tb.x + sb.y * tb.y + sb.z * tb.z + sb.w * tb.w;
    union { ushort4 h[2]; uint4 u; } pk;
    pk.h[0].x = f2bf(sa.x * SCALE2); pk.h[0].y = f2bf(sa.y * SCALE2);
    pk.h[0].z = f2bf(sa.z * SCALE2); pk.h[0].w = f2bf(sa.w * SCALE2);
    pk.h[1].x = f2bf(sb.x * SCALE2); pk.h[1].y = f2bf(sb.y * SCALE2);
    pk.h[1].z = f2bf(sb.z * SCALE2); pk.h[1].w = f2bf(sb.w * SCALE2);
    wsrc[j * 16] = pk.u;
    pk.h[0].x = f2bf(ta.x); pk.h[0].y = f2bf(ta.y);
    pk.h[0].z = f2bf(ta.z); pk.h[0].w = f2bf(ta.w);
    pk.h[1].x = f2bf(tb.x); pk.h[1].y = f2bf(tb.y);
    pk.h[1].z = f2bf(tb.z); pk.h[1].w = f2bf(tb.w);
    wtgt[j * 16] = pk.u;
  }
  d += __shfl_xor(d, 1, 64);
  d += __shfl_xor(d, 2, 64);
  d += __shfl_xor(d, 4, 64);
  if (kg == 0) pos[tl * 16 + row16] = d * SCALE;
}

// ---- k_aux: 2 roles ----
__global__ __launch_bounds__(256) void k_aux(const float* __restrict__ src,
                                             const float* __restrict__ tgt,
                                             const int* __restrict__ classes,
                                             unsigned short* __restrict__ tgtb,
                                             unsigned short* __restrict__ srcb,
                                             float* __restrict__ pos,
                                             int* __restrict__ outpos,
                                             int* __restrict__ counts) {
  int blk = blockIdx.x;
  if (blk < 512) {
    aux_copy_body(src, tgt, tgtb, srcb, pos, blk, threadIdx.x);
    return;
  }

  __shared__ int sa[MAXC * 256];
  __shared__ int sb2[MAXC * 256];
  int b = blk - 512, t = threadIdx.x;
  int base = b * NPATCH + t * 16;
  int cv[16];
#pragma unroll
  for (int e = 0; e < 16; ++e) cv[e] = classes[base + e];
  int cnt[MAXC];
#pragma unroll
  for (int c = 0; c < MAXC; ++c) {
    cnt[c] = 0;
#pragma unroll
    for (int e = 0; e < 16; ++e)
      if (cv[e] == c) cnt[c]++;
  }
#pragma unroll
  for (int c = 0; c < MAXC; ++c) sa[c * 256 + t] = cnt[c];
  __syncthreads();

  int* rp = sa; int* wp = sb2;
  for (int d = 1; d < 256; d <<= 1) {
#pragma unroll
    for (int c = 0; c < MAXC; ++c) {
      int v = rp[c * 256 + t];
      if (t >= d) v += rp[c * 256 + t - d];
      wp[c * 256 + t] = v;
    }
    __syncthreads();
    int* tmp = rp; rp = wp; wp = tmp;
  }

  int tot[MAXC], excl[MAXC], off[MAXC + 1];
  off[0] = 0;
#pragma unroll
  for (int c = 0; c < MAXC; ++c) {
    tot[c]  = rp[c * 256 + 255];
    excl[c] = rp[c * 256 + t] - cnt[c];
    off[c + 1] = off[c] + tot[c];
  }
#pragma unroll
  for (int c = 0; c < MAXC; ++c) {
    int r = off[c] + excl[c];
#pragma unroll
    for (int e = 0; e < 16; ++e)
      if (cv[e] == c) { outpos[base + e] = r; r++; }
  }
  if (t < MAXC) counts[b * MAXC + t] = tot[t];
}

// ---------------- main fused GEMM + online lse stats -----------------------------------
// R7: deep pipeline (T3/T4).  R6 probes: GEMM-only = 26.6us (1.25us/tile ~= 3000cy vs
// ~500cy issue floor) -> latency-bound, not issue-bound.  Culprit: per-tile
// __syncthreads implicitly drains vmcnt(0), waiting on stage loads issued only ~400cy
// earlier (< L2/L3 latency 200-900cy) + 4-wave phase lockstep.  Fix: 3 LDS buffers,
// stage tile t+2 each iter, barrier = "s_waitcnt vmcnt(4); s_barrier" -- the 4 loads
// for t+2 stay in flight across the barrier; t+1's (issued a full tile ago, ~2500cy)
// must be done.  Race-check: STAGE into (t+2)%3 touches the buffer read at t-1,
// separated by a barrier; ds_reads complete before the barrier via MFMA data deps.
// STATS / masking / grid / k_aux / k_fin unchanged (one variable).
__global__ __launch_bounds__(256, 3) void k_main(const unsigned short* __restrict__ srcb,
                                                 const unsigned short* __restrict__ tgtb,
                                                 const int* __restrict__ classes,
                                                 float* __restrict__ pm,
                                                 float* __restrict__ ps) {
  __shared__ u32x4 sB[3][1024];               // 3 x 16KB B-tile buffers

  const int p   = blockIdx.x;
  const int b   = p & 3;
  const int jl  = (p >> 2) & 1;
  const int rb  = (p >> 3) & 31;
  const int top = p >> 8;                     // 0..2
  const int j   = top * 2 + jl;               // 0..5
  const int t0  = (j * 64) / 3;               // 32-col tile range [t0, t1) of 128
  const int t1  = ((j + 1) * 64) / 3;         // chunks: 21,21,22,21,21,22
  const int nt  = t1 - t0;

  const int tid  = threadIdx.x;
  const int w    = tid >> 6;                  // wave 0..3 -> rowgroup
  const int lane = tid & 63;
  const int q = lane >> 4, l4 = lane & 15;
  const int rowstart = b * NPATCH + rb * 128 + w * 32;

  // ---- A fragments: 32 rows resident per wave (16 coalesced uint4 loads), pinned
  const u32x4* ap = (const u32x4*)srcb + (size_t)(b * 256 + rb * 8 + w * 2) * 512 + lane;
  u32x4 afr[2][8];
#pragma unroll
  for (int rt = 0; rt < 2; ++rt)
#pragma unroll
    for (int ks = 0; ks < 8; ++ks)
      afr[rt][ks] = ap[rt * 512 + ks * 64];
#pragma unroll
  for (int rt = 0; rt < 2; ++rt)
#pragma unroll
    for (int ks = 0; ks < 8; ++ks)
      asm volatile("" : "+v"(afr[rt][ks]));

  int rcls[2][4];
#pragma unroll
  for (int rt = 0; rt < 2; ++rt)
#pragma unroll
    for (int r = 0; r < 4; ++r) {
      rcls[rt][r] = classes[rowstart + rt * 16 + q * 4 + r];
      asm volatile("" : "+v"(rcls[rt][r]));
    }

  float m_[2][4], s_[2][4];
#pragma unroll
  for (int rt = 0; rt < 2; ++rt)
#pragma unroll
    for (int r = 0; r < 4; ++r) { m_[rt][r] = -INFINITY; s_[rt][r] = 0.f; }

  const u32x4* bstage = (const u32x4*)tgtb + (size_t)(b * 256 + t0 * 2) * 512
                      + w * 64 + lane;
  const int* clp = classes + b * NPATCH + t0 * 32 + l4;

#define STAGE(NB, IT)                                                               \
  {                                                                                 \
    const u32x4* g = bstage + (size_t)(IT) * 1024;                                  \
    _Pragma("unroll")                                                               \
    for (int r = 0; r < 4; ++r)                                                     \
      glds16(g + r * 256, &sB[NB][(r * 4 + w) * 64]);                               \
  }

#define STATS(ac, cc0, cc1)                                                         \
  {                                                                                 \
    _Pragma("unroll")                                                               \
    for (int rt = 0; rt < 2; ++rt) {                                                \
      _Pragma("unroll")                                                             \
      for (int r = 0; r < 4; ++r) {                                                 \
        int rc = rcls[rt][r];                                                       \
        float y0 = ((cc0) == rc) ? NEGH : (ac)[rt][0][r];                           \
        float y1 = ((cc1) == rc) ? NEGH : (ac)[rt][1][r];                           \
        float nm = fmaxf(m_[rt][r], fmaxf(y0, y1));                                 \
        float e01 = fexp2(y0 - nm) + fexp2(y1 - nm);                                \
        s_[rt][r] = fmaf(s_[rt][r], fexp2(m_[rt][r] - nm), e01);                    \
        m_[rt][r] = nm;                                                             \
      }                                                                             \
    }                                                                               \
  }

  const f32x4 zc = {0.f, 0.f, 0.f, 0.f};

  STAGE(0, 0);                                // prologue: tiles 0,1 -> bufs 0,1
  STAGE(1, 1);
  // wait buf0 (oldest 4 loads); buf1's 4 may stay in flight
  asm volatile("s_waitcnt vmcnt(4)\n\ts_barrier" ::: "memory");

  for (int it = 0; it < nt; ++it) {
    const int cb = it % 3;
    const bool staged = (it + 2 < nt);
    if (staged) STAGE((it + 2) % 3, it + 2);  // 2-deep prefetch

    int c0 = clp[0];                          // this tile's column classes
    int c1 = clp[16];
    clp += 32;

    f32x4 acc[2][2];
    {                                         // kh = 0
      u32x4 e0[4], e1[4];
#pragma unroll
      for (int i = 0; i < 4; ++i) {
        e0[i] = sB[cb][i * 64 + lane];
        e1[i] = sB[cb][512 + i * 64 + lane];
      }
#pragma unroll
      for (int ksl = 0; ksl < 4; ++ksl) {
        short8 b0 = __builtin_bit_cast(short8, e0[ksl]);
        short8 b1 = __builtin_bit_cast(short8, e1[ksl]);
#pragma unroll
        for (int rt = 0; rt < 2; ++rt) {
          short8 a = __builtin_bit_cast(short8, afr[rt][ksl]);
          acc[rt][0] = __builtin_amdgcn_mfma_f32_16x16x32_bf16(
              a, b0, (ksl == 0) ? zc : acc[rt][0], 0, 0, 0);
          acc[rt][1] = __builtin_amdgcn_mfma_f32_16x16x32_bf16(
              a, b1, (ksl == 0) ? zc : acc[rt][1], 0, 0, 0);
        }
      }
    }
    {                                         // kh = 1
      u32x4 e0[4], e1[4];
#pragma unroll
      for (int i = 0; i < 4; ++i) {
        e0[i] = sB[cb][256 + i * 64 + lane];
        e1[i] = sB[cb][768 + i * 64 + lane];
      }
#pragma unroll
      for (int ksl = 0; ksl < 4; ++ksl) {
        short8 b0 = __builtin_bit_cast(short8, e0[ksl]);
        short8 b1 = __builtin_bit_cast(short8, e1[ksl]);
#pragma unroll
        for (int rt = 0; rt < 2; ++rt) {
          short8 a = __builtin_bit_cast(short8, afr[rt][4 + ksl]);
          acc[rt][0] = __builtin_amdgcn_mfma_f32_16x16x32_bf16(a, b0, acc[rt][0], 0, 0, 0);
          acc[rt][1] = __builtin_amdgcn_mfma_f32_16x16x32_bf16(a, b1, acc[rt][1], 0, 0, 0);
        }
      }
    }

    STATS(acc, c0, c1);

    if (it + 1 < nt) {
      // counted-vmcnt barrier: keep this iter's 4 stage loads (tile it+2) in flight;
      // require tile it+1's loads (issued last iter) to have landed.
      if (staged) asm volatile("s_waitcnt vmcnt(4)\n\ts_barrier" ::: "memory");
      else        asm volatile("s_waitcnt vmcnt(0)\n\ts_barrier" ::: "memory");
    }
  }
#undef STAGE
#undef STATS

  // butterfly merge across the 16 col-lanes of each quad
#pragma unroll
  for (int off = 1; off < 16; off <<= 1) {
#pragma unroll
    for (int rt = 0; rt < 2; ++rt)
#pragma unroll
      for (int r = 0; r < 4; ++r) {
        float om = __shfl_xor(m_[rt][r], off, 64);
        float os = __shfl_xor(s_[rt][r], off, 64);
        float nm = fmaxf(m_[rt][r], om);
        s_[rt][r] = s_[rt][r] * fexp2(m_[rt][r] - nm) + os * fexp2(om - nm);
        m_[rt][r] = nm;
      }
  }

  if (l4 == 0) {
#pragma unroll
    for (int rt = 0; rt < 2; ++rt)
#pragma unroll
      for (int r = 0; r < 4; ++r) {
        size_t o = (size_t)j * NROWS + rowstart + rt * 16 + q * 4 + r;
        pm[o] = m_[rt][r];                     // log2 domain
        ps[o] = s_[rt][r];
      }
  }
}

// ---------------- final: merge chunk partials + pad term + scatter (grid 64) ----------
__global__ __launch_bounds__(256) void k_fin(const int* __restrict__ classes,
                                             const float* __restrict__ pos,
                                             const float* __restrict__ pm,
                                             const float* __restrict__ ps,
                                             const int* __restrict__ outpos,
                                             const int* __restrict__ counts,
                                             float* __restrict__ out) {
  int n = blockIdx.x * 256 + threadIdx.x;
  int b = n >> 12;
  int c = classes[n];
  float ps_ = pos[n];

  float M2 = -INFINITY;
  float mm[NCHUNK], ss[NCHUNK];
#pragma unroll
  for (int s = 0; s < NCHUNK; ++s) {
    mm[s] = pm[(size_t)s * NROWS + n];
    ss[s] = ps[(size_t)s * NROWS + n];
    M2 = fmaxf(M2, mm[s]);
  }
  float S2 = 0.f;
#pragma unroll
  for (int s = 0; s < NCHUNK; ++s) S2 = fmaf(ss[s], fexp2(mm[s] - M2), S2);
  float ln = (S2 > 0.f) ? (M2 + flog2(S2)) * LN2F : -INFINITY;

  int npad = counts[b * MAXC + c] - 1;
  float pt = (npad > 0) ? (logf((float)npad) + NEGFILL_T) : -INFINITY;
  float M = fmaxf(ps_, fmaxf(ln, pt));
  float lse = M + logf(expf(ps_ - M) + expf(ln - M) + expf(pt - M));
  out[b * NPATCH + outpos[n]] = lse - ps_;
}

extern "C" void kernel_launch(void* const* d_in, const int* in_sizes, int n_in,
                              void* d_out, int out_size, void* d_ws, size_t ws_size,
                              hipStream_t stream) {
  const float* src = (const float*)d_in[0];
  const float* tgt = (const float*)d_in[1];
  const int* cls   = (const int*)d_in[2];
  float* out = (float*)d_out;

  char* ws = (char*)d_ws;
  unsigned short* tgtb = (unsigned short*)(ws);            //  8,388,608 B (fragment layout)
  unsigned short* srcb = (unsigned short*)(ws + 8388608);  //  8,388,608 B (frag, pre-scaled)
  float* pos    = (float*)(ws + 16777216);                 //     65,536 B
  float* pm     = (float*)(ws + 16842752);                 //    393,216 B (6 chunk planes)
  float* ps     = (float*)(ws + 17235968);                 //    393,216 B
  int*   outpos = (int*)  (ws + 17629184);                 //     65,536 B
  int*   counts = (int*)  (ws + 17694720);                 //         80 B

  k_aux<<<512 + NBATCH, 256, 0, stream>>>(src, tgt, cls, tgtb, srcb, pos, outpos, counts);
  k_main<<<GRID_MAIN, 256, 0, stream>>>(srcb, tgtb, cls, pm, ps);
  k_fin<<<NROWS / 256, 256, 0, stream>>>(cls, pos, pm, ps, outpos, counts, out);
}

// Round 9
// 128.035 us; speedup vs baseline: 2.2552x; 1.0008x over previous
//
#include <hip/hip_runtime.h>
#include <cstdint>

#define NBATCH 4
#define NPATCH 4096
#define MAXC   5
#define NCHUNK 6                            /* col chunks (j) */
#define RBLOCKS 32                          /* 128-row blocks per batch */
#define GRID_MAIN (NBATCH * RBLOCKS * NCHUNK)   /* 768 4-wave blocks = 3/CU */
#define SCALE  14.285714285714286f          /* 1/T, T=0.07 */
#define SCALE2 20.609929006188747f          /* (1/T) * log2(e) */
#define LN2F   0.6931471805599453f
#define NEGH  -1.0e38f
#define NEGFILL_T -142.85714285714286f      /* NEG_FILL / T */
#define NROWS (NBATCH * NPATCH)

typedef __attribute__((ext_vector_type(8))) short short8;   // 8 bf16 (4 VGPRs)
typedef __attribute__((ext_vector_type(4))) float f32x4;
typedef __attribute__((ext_vector_type(4))) unsigned int u32x4;

__device__ __forceinline__ float fexp2(float x) { return __builtin_amdgcn_exp2f(x); }
__device__ __forceinline__ float flog2(float x) { return __builtin_amdgcn_logf(x); }  // v_log_f32 = log2

__device__ __forceinline__ unsigned short f2bf(float f) {
  uint32_t u = __builtin_bit_cast(uint32_t, f);
  u = (u + 0x7FFFu + ((u >> 16) & 1u)) >> 16;   // RNE
  return (unsigned short)u;
}

// async global->LDS, 16B per lane; LDS dest is wave-uniform base + lane*16
__device__ __forceinline__ void glds16(const void* g, void* l) {
  __builtin_amdgcn_global_load_lds(
      (const __attribute__((address_space(1))) uint32_t*)g,
      (__attribute__((address_space(3))) uint32_t*)l, 16, 0, 0);
}

// Fragment layout (srcb and tgtb): tile = 16 rows x 256 k (8 KB).
// 16B chunk (8 bf16, one row's k-octet) at uint4 index  tile*512 + kc*16 + row16.

// ---- k_aux: 2 roles ----
// R8: the copy phase's direct fragment-layout stores were 16B/lane at 1KB stride
// (25% line utilization + RMW => ~4x write traffic; est ~30-45us for an 8us-roofline
// kernel; e2e minus k_main has been a stable ~79us across R2/R4/R7).  Fix: LDS
// transpose -- read pattern unchanged (line-efficient), bf16 fragments staged into
// LDS (pitch-17 u4: write conflicts ~4-way, reads uniform), then 128 consecutive
// lanes store 2KB contiguous spans of the fragment layout (fully coalesced).
__global__ __launch_bounds__(256) void k_aux(const float* __restrict__ src,
                                             const float* __restrict__ tgt,
                                             const int* __restrict__ classes,
                                             unsigned short* __restrict__ tgtb,
                                             unsigned short* __restrict__ srcb,
                                             float* __restrict__ pos,
                                             int* __restrict__ outpos,
                                             int* __restrict__ counts) {
  int blk = blockIdx.x;
  if (blk < 512) {
    __shared__ uint4 sS[2][544], sT[2][544];   // pitch 17 u4 per kc (32 kc x 16 rows)
    int t    = threadIdx.x;
    int half = t >> 7;                         // which tile of the pair
    int tt   = t & 127;
    int tl   = blk * 2 + half;
    int row16 = tt >> 3;                       // 0..15 (read mapping unchanged)
    int kg    = tt & 7;                        // 32-k slab
    size_t rowbase = (size_t)(tl * 16 + row16) * 256 + kg * 32;
    const float4* rs  = (const float4*)(src + rowbase);
    const float4* rt_ = (const float4*)(tgt + rowbase);
    float d = 0.f;
#pragma unroll
    for (int jj = 0; jj < 4; ++jj) {           // chunk kc = kg*4 + jj
      float4 sa = rs[jj * 2], sb = rs[jj * 2 + 1];
      float4 ta = rt_[jj * 2], tb = rt_[jj * 2 + 1];
      d += sa.x * ta.x + sa.y * ta.y + sa.z * ta.z + sa.w * ta.w
         + sb.x * tb.x + sb.y * tb.y + sb.z * tb.z + sb.w * tb.w;
      union { ushort4 h[2]; uint4 u; } pk;
      int li = (kg * 4 + jj) * 17 + row16;
      pk.h[0].x = f2bf(sa.x * SCALE2); pk.h[0].y = f2bf(sa.y * SCALE2);
      pk.h[0].z = f2bf(sa.z * SCALE2); pk.h[0].w = f2bf(sa.w * SCALE2);
      pk.h[1].x = f2bf(sb.x * SCALE2); pk.h[1].y = f2bf(sb.y * SCALE2);
      pk.h[1].z = f2bf(sb.z * SCALE2); pk.h[1].w = f2bf(sb.w * SCALE2);
      sS[half][li] = pk.u;
      pk.h[0].x = f2bf(ta.x); pk.h[0].y = f2bf(ta.y);
      pk.h[0].z = f2bf(ta.z); pk.h[0].w = f2bf(ta.w);
      pk.h[1].x = f2bf(tb.x); pk.h[1].y = f2bf(tb.y);
      pk.h[1].z = f2bf(tb.z); pk.h[1].w = f2bf(tb.w);
      sT[half][li] = pk.u;
    }
    d += __shfl_xor(d, 1, 64);
    d += __shfl_xor(d, 2, 64);
    d += __shfl_xor(d, 4, 64);
    if (kg == 0) pos[tl * 16 + row16] = d * SCALE;

    __syncthreads();
    // coalesced store: 128 consecutive lanes cover 2KB contiguous fragment span
    uint4* osrc = (uint4*)srcb + (size_t)tl * 512;
    uint4* otgt = (uint4*)tgtb + (size_t)tl * 512;
#pragma unroll
    for (int c = 0; c < 4; ++c) {
      int g  = c * 128 + tt;                   // u4 index within tile (0..511)
      int li = (g >> 4) * 17 + (g & 15);
      osrc[g] = sS[half][li];
      otgt[g] = sT[half][li];
    }
    return;
  }

  __shared__ int sa[MAXC * 256];
  __shared__ int sb2[MAXC * 256];
  int b = blk - 512, t = threadIdx.x;
  int base = b * NPATCH + t * 16;
  int cv[16];
#pragma unroll
  for (int e = 0; e < 16; ++e) cv[e] = classes[base + e];
  int cnt[MAXC];
#pragma unroll
  for (int c = 0; c < MAXC; ++c) {
    cnt[c] = 0;
#pragma unroll
    for (int e = 0; e < 16; ++e)
      if (cv[e] == c) cnt[c]++;
  }
#pragma unroll
  for (int c = 0; c < MAXC; ++c) sa[c * 256 + t] = cnt[c];
  __syncthreads();

  int* rp = sa; int* wp = sb2;
  for (int d = 1; d < 256; d <<= 1) {
#pragma unroll
    for (int c = 0; c < MAXC; ++c) {
      int v = rp[c * 256 + t];
      if (t >= d) v += rp[c * 256 + t - d];
      wp[c * 256 + t] = v;
    }
    __syncthreads();
    int* tmp = rp; rp = wp; wp = tmp;
  }

  int tot[MAXC], excl[MAXC], off[MAXC + 1];
  off[0] = 0;
#pragma unroll
  for (int c = 0; c < MAXC; ++c) {
    tot[c]  = rp[c * 256 + 255];
    excl[c] = rp[c * 256 + t] - cnt[c];
    off[c + 1] = off[c] + tot[c];
  }
#pragma unroll
  for (int c = 0; c < MAXC; ++c) {
    int r = off[c] + excl[c];
#pragma unroll
    for (int e = 0; e < 16; ++e)
      if (cv[e] == c) { outpos[base + e] = r; r++; }
  }
  if (t < MAXC) counts[b * MAXC + t] = tot[t];
}

// ---------------- main fused GEMM + online lse stats (R7 frozen) -----------------------
// Measured: GEMM-only 26.6us (probe), full 48.8us.  GEMM side sits at ~77% of the
// per-CU LDS-read ceiling (12 waves x 16KB/tile @ ~85B/cy) and ~62% of the MFMA pipe;
// pipeline depth (R7) and barrier drain are NOT the limiter.  Frozen this round.
__global__ __launch_bounds__(256, 3) void k_main(const unsigned short* __restrict__ srcb,
                                                 const unsigned short* __restrict__ tgtb,
                                                 const int* __restrict__ classes,
                                                 float* __restrict__ pm,
                                                 float* __restrict__ ps) {
  __shared__ u32x4 sB[3][1024];               // 3 x 16KB B-tile buffers

  const int p   = blockIdx.x;
  const int b   = p & 3;
  const int jl  = (p >> 2) & 1;
  const int rb  = (p >> 3) & 31;
  const int top = p >> 8;                     // 0..2
  const int j   = top * 2 + jl;               // 0..5
  const int t0  = (j * 64) / 3;               // 32-col tile range [t0, t1) of 128
  const int t1  = ((j + 1) * 64) / 3;         // chunks: 21,21,22,21,21,22
  const int nt  = t1 - t0;

  const int tid  = threadIdx.x;
  const int w    = tid >> 6;                  // wave 0..3 -> rowgroup
  const int lane = tid & 63;
  const int q = lane >> 4, l4 = lane & 15;
  const int rowstart = b * NPATCH + rb * 128 + w * 32;

  // ---- A fragments: 32 rows resident per wave (16 coalesced uint4 loads), pinned
  const u32x4* ap = (const u32x4*)srcb + (size_t)(b * 256 + rb * 8 + w * 2) * 512 + lane;
  u32x4 afr[2][8];
#pragma unroll
  for (int rt = 0; rt < 2; ++rt)
#pragma unroll
    for (int ks = 0; ks < 8; ++ks)
      afr[rt][ks] = ap[rt * 512 + ks * 64];
#pragma unroll
  for (int rt = 0; rt < 2; ++rt)
#pragma unroll
    for (int ks = 0; ks < 8; ++ks)
      asm volatile("" : "+v"(afr[rt][ks]));

  int rcls[2][4];
#pragma unroll
  for (int rt = 0; rt < 2; ++rt)
#pragma unroll
    for (int r = 0; r < 4; ++r) {
      rcls[rt][r] = classes[rowstart + rt * 16 + q * 4 + r];
      asm volatile("" : "+v"(rcls[rt][r]));
    }

  float m_[2][4], s_[2][4];
#pragma unroll
  for (int rt = 0; rt < 2; ++rt)
#pragma unroll
    for (int r = 0; r < 4; ++r) { m_[rt][r] = -INFINITY; s_[rt][r] = 0.f; }

  const u32x4* bstage = (const u32x4*)tgtb + (size_t)(b * 256 + t0 * 2) * 512
                      + w * 64 + lane;
  const int* clp = classes + b * NPATCH + t0 * 32 + l4;

#define STAGE(NB, IT)                                                               \
  {                                                                                 \
    const u32x4* g = bstage + (size_t)(IT) * 1024;                                  \
    _Pragma("unroll")                                                               \
    for (int r = 0; r < 4; ++r)                                                     \
      glds16(g + r * 256, &sB[NB][(r * 4 + w) * 64]);                               \
  }

#define STATS(ac, cc0, cc1)                                                         \
  {                                                                                 \
    _Pragma("unroll")                                                               \
    for (int rt = 0; rt < 2; ++rt) {                                                \
      _Pragma("unroll")                                                             \
      for (int r = 0; r < 4; ++r) {                                                 \
        int rc = rcls[rt][r];                                                       \
        float y0 = ((cc0) == rc) ? NEGH : (ac)[rt][0][r];                           \
        float y1 = ((cc1) == rc) ? NEGH : (ac)[rt][1][r];                           \
        float nm = fmaxf(m_[rt][r], fmaxf(y0, y1));                                 \
        float e01 = fexp2(y0 - nm) + fexp2(y1 - nm);                                \
        s_[rt][r] = fmaf(s_[rt][r], fexp2(m_[rt][r] - nm), e01);                    \
        m_[rt][r] = nm;                                                             \
      }                                                                             \
    }                                                                               \
  }

  const f32x4 zc = {0.f, 0.f, 0.f, 0.f};

  STAGE(0, 0);                                // prologue: tiles 0,1 -> bufs 0,1
  STAGE(1, 1);
  asm volatile("s_waitcnt vmcnt(4)\n\ts_barrier" ::: "memory");

  for (int it = 0; it < nt; ++it) {
    const int cb = it % 3;
    const bool staged = (it + 2 < nt);
    if (staged) STAGE((it + 2) % 3, it + 2);  // 2-deep prefetch

    int c0 = clp[0];                          // this tile's column classes
    int c1 = clp[16];
    clp += 32;

    f32x4 acc[2][2];
    {                                         // kh = 0
      u32x4 e0[4], e1[4];
#pragma unroll
      for (int i = 0; i < 4; ++i) {
        e0[i] = sB[cb][i * 64 + lane];
        e1[i] = sB[cb][512 + i * 64 + lane];
      }
#pragma unroll
      for (int ksl = 0; ksl < 4; ++ksl) {
        short8 b0 = __builtin_bit_cast(short8, e0[ksl]);
        short8 b1 = __builtin_bit_cast(short8, e1[ksl]);
#pragma unroll
        for (int rt = 0; rt < 2; ++rt) {
          short8 a = __builtin_bit_cast(short8, afr[rt][ksl]);
          acc[rt][0] = __builtin_amdgcn_mfma_f32_16x16x32_bf16(
              a, b0, (ksl == 0) ? zc : acc[rt][0], 0, 0, 0);
          acc[rt][1] = __builtin_amdgcn_mfma_f32_16x16x32_bf16(
              a, b1, (ksl == 0) ? zc : acc[rt][1], 0, 0, 0);
        }
      }
    }
    {                                         // kh = 1
      u32x4 e0[4], e1[4];
#pragma unroll
      for (int i = 0; i < 4; ++i) {
        e0[i] = sB[cb][256 + i * 64 + lane];
        e1[i] = sB[cb][768 + i * 64 + lane];
      }
#pragma unroll
      for (int ksl = 0; ksl < 4; ++ksl) {
        short8 b0 = __builtin_bit_cast(short8, e0[ksl]);
        short8 b1 = __builtin_bit_cast(short8, e1[ksl]);
#pragma unroll
        for (int rt = 0; rt < 2; ++rt) {
          short8 a = __builtin_bit_cast(short8, afr[rt][4 + ksl]);
          acc[rt][0] = __builtin_amdgcn_mfma_f32_16x16x32_bf16(a, b0, acc[rt][0], 0, 0, 0);
          acc[rt][1] = __builtin_amdgcn_mfma_f32_16x16x32_bf16(a, b1, acc[rt][1], 0, 0, 0);
        }
      }
    }

    STATS(acc, c0, c1);

    if (it + 1 < nt) {
      if (staged) asm volatile("s_waitcnt vmcnt(4)\n\ts_barrier" ::: "memory");
      else        asm volatile("s_waitcnt vmcnt(0)\n\ts_barrier" ::: "memory");
    }
  }
#undef STAGE
#undef STATS

  // butterfly merge across the 16 col-lanes of each quad
#pragma unroll
  for (int off = 1; off < 16; off <<= 1) {
#pragma unroll
    for (int rt = 0; rt < 2; ++rt)
#pragma unroll
      for (int r = 0; r < 4; ++r) {
        float om = __shfl_xor(m_[rt][r], off, 64);
        float os = __shfl_xor(s_[rt][r], off, 64);
        float nm = fmaxf(m_[rt][r], om);
        s_[rt][r] = s_[rt][r] * fexp2(m_[rt][r] - nm) + os * fexp2(om - nm);
        m_[rt][r] = nm;
      }
  }

  if (l4 == 0) {
#pragma unroll
    for (int rt = 0; rt < 2; ++rt)
#pragma unroll
      for (int r = 0; r < 4; ++r) {
        size_t o = (size_t)j * NROWS + rowstart + rt * 16 + q * 4 + r;
        pm[o] = m_[rt][r];                     // log2 domain
        ps[o] = s_[rt][r];
      }
  }
}

// ---------------- final: merge chunk partials + pad term + scatter (grid 64) ----------
__global__ __launch_bounds__(256) void k_fin(const int* __restrict__ classes,
                                             const float* __restrict__ pos,
                                             const float* __restrict__ pm,
                                             const float* __restrict__ ps,
                                             const int* __restrict__ outpos,
                                             const int* __restrict__ counts,
                                             float* __restrict__ out) {
  int n = blockIdx.x * 256 + threadIdx.x;
  int b = n >> 12;
  int c = classes[n];
  float ps_ = pos[n];

  float M2 = -INFINITY;
  float mm[NCHUNK], ss[NCHUNK];
#pragma unroll
  for (int s = 0; s < NCHUNK; ++s) {
    mm[s] = pm[(size_t)s * NROWS + n];
    ss[s] = ps[(size_t)s * NROWS + n];
    M2 = fmaxf(M2, mm[s]);
  }
  float S2 = 0.f;
#pragma unroll
  for (int s = 0; s < NCHUNK; ++s) S2 = fmaf(ss[s], fexp2(mm[s] - M2), S2);
  float ln = (S2 > 0.f) ? (M2 + flog2(S2)) * LN2F : -INFINITY;

  int npad = counts[b * MAXC + c] - 1;
  float pt = (npad > 0) ? (logf((float)npad) + NEGFILL_T) : -INFINITY;
  float M = fmaxf(ps_, fmaxf(ln, pt));
  float lse = M + logf(expf(ps_ - M) + expf(ln - M) + expf(pt - M));
  out[b * NPATCH + outpos[n]] = lse - ps_;
}

extern "C" void kernel_launch(void* const* d_in, const int* in_sizes, int n_in,
                              void* d_out, int out_size, void* d_ws, size_t ws_size,
                              hipStream_t stream) {
  const float* src = (const float*)d_in[0];
  const float* tgt = (const float*)d_in[1];
  const int* cls   = (const int*)d_in[2];
  float* out = (float*)d_out;

  char* ws = (char*)d_ws;
  unsigned short* tgtb = (unsigned short*)(ws);            //  8,388,608 B (fragment layout)
  unsigned short* srcb = (unsigned short*)(ws + 8388608);  //  8,388,608 B (frag, pre-scaled)
  float* pos    = (float*)(ws + 16777216);                 //     65,536 B
  float* pm     = (float*)(ws + 16842752);                 //    393,216 B (6 chunk planes)
  float* ps     = (float*)(ws + 17235968);                 //    393,216 B
  int*   outpos = (int*)  (ws + 17629184);                 //     65,536 B
  int*   counts = (int*)  (ws + 17694720);                 //         80 B

  k_aux<<<512 + NBATCH, 256, 0, stream>>>(src, tgt, cls, tgtb, srcb, pos, outpos, counts);
  k_main<<<GRID_MAIN, 256, 0, stream>>>(srcb, tgtb, cls, pm, ps);
  k_fin<<<NROWS / 256, 256, 0, stream>>>(cls, pos, pm, ps, outpos, counts, out);
}